// Round 8
// baseline (706.041 us; speedup 1.0000x reference)
//
#include <hip/hip_runtime.h>
#include <cfloat>
#include <cmath>

// PillarEncoder (MI355X / gfx950): out[b][c][y][x] = (4, 64, 496, 432) fp32
// R8 = MEASUREMENT ROUND: kernels repeated (REP) so each clears the ~130us
// poison-fill floor and appears in rocprof top-5. True dur = shown/REP.
#define XL 432
#define YL 496
#define NCH 64
#define HIMG 192
#define WIMG 640
#define HW (HIMG * WIMG)     // 122880
#define PTS_M 32

#define WAVES 16             // 1024 threads/block (pillar kernel)
#define TPB (WAVES * 64)
#define PPG 4                // pillars per wave-group
#define NBLOCKS 256
#define WPITCH 132           // padded weight row pitch (floats)

typedef const __attribute__((address_space(1))) void* gas_t;
typedef __attribute__((address_space(3))) void* las_t;

__device__ __forceinline__ void gload_lds16(const float* g, float* l) {
    __builtin_amdgcn_global_load_lds((gas_t)g, (las_t)l, 16, 0, 0);
}

#define RED5(v) { v += __shfl_xor(v, 16); v += __shfl_xor(v, 8); v += __shfl_xor(v, 4); \
                  v += __shfl_xor(v, 2);  v += __shfl_xor(v, 1); }

// ---------------------------------------------------------------- zerofill
__global__ void zerofill(float4* __restrict__ o, int n4) {
    int i = blockIdx.x * blockDim.x + threadIdx.x;
    const int st = gridDim.x * blockDim.x;
    const float4 z = make_float4(0.f, 0.f, 0.f, 0.f);
    for (; i < n4; i += st) o[i] = z;
}

// ------------------------------------------- K0: NCHW -> NHWC, float4 both sides
template<int REP>
__global__ __launch_bounds__(256, 2) void transpose4(
    const float* __restrict__ img, float* __restrict__ imgT, int B)
{
    __shared__ float tt[4][64][65];          // 66,560 B -> 2 blocks/CU
    const int tid = threadIdx.x;
    const int NT = HW / 256;                 // 480 tiles/batch (64c x 256px)
    for (int rep = 0; rep < REP; ++rep)
    for (int tile = blockIdx.x; tile < B * NT; tile += gridDim.x) {
        const int b   = tile / NT;
        const int px0 = (tile - b * NT) * 256;
        __syncthreads();                     // prev tile's LDS reads done
        const float4* base4 = (const float4*)(img + (size_t)b * NCH * HW) + px0 / 4;
        #pragma unroll
        for (int i = tid; i < 64 * 64; i += 256) {      // c x f4
            const int c = i >> 6, f4 = i & 63;
            const float4 v = base4[(size_t)c * (HW / 4) + f4];
            tt[0][c][f4] = v.x; tt[1][c][f4] = v.y;
            tt[2][c][f4] = v.z; tt[3][c][f4] = v.w;     // px = 4*f4 + j
        }
        __syncthreads();
        float4* ob4 = (float4*)(imgT + ((size_t)b * HW + px0) * NCH);
        #pragma unroll
        for (int i = tid; i < 256 * 16; i += 256) {     // hw x c4
            const int c4 = i & 15, hw = i >> 4;
            const int j = hw & 3, f4 = hw >> 2;
            float4 o;
            o.x = tt[j][4*c4+0][f4]; o.y = tt[j][4*c4+1][f4];
            o.z = tt[j][4*c4+2][f4]; o.w = tt[j][4*c4+3][f4];
            ob4[(size_t)hw * 16 + c4] = o;
        }
    }
}

// ---------------------------------------------------------------- pillar pieces
struct ChanConst {
    float As, Bs, Cs, Ds, w07, w18, w4s, w5s, w6s, tch;
    float b1a, b1b, lga, lgb, lba, lbb, gb2;
};

__device__ __forceinline__ ChanConst load_chan_consts(
    int lane, const float* conv_w, const float* bng, const float* bnb,
    const float* bnm, const float* bnv, const float* b1, const float* lng,
    const float* lnb, const float* b2)
{
    ChanConst cc;
    float cw[9];
    #pragma unroll
    for (int i = 0; i < 9; ++i) cw[i] = conv_w[lane * 9 + i];
    const float s = bng[lane] / sqrtf(bnv[lane] + 1e-3f);
    cc.tch = bnb[lane] - bnm[lane] * s;
    cc.As  = (cw[0] + cw[4] + cw[7]) * s;
    cc.Bs  = (cw[1] + cw[5] + cw[8]) * s;
    cc.Cs  = (cw[2] + cw[6]) * s;
    cc.Ds  = cw[3] * s;
    cc.w07 = (cw[0] + cw[7]) * s;
    cc.w18 = (cw[1] + cw[8]) * s;
    cc.w4s = cw[4] * s; cc.w5s = cw[5] * s; cc.w6s = cw[6] * s;
    cc.b1a = b1[lane];  cc.b1b = b1[lane + 64];
    cc.lga = lng[lane]; cc.lgb = lng[lane + 64];
    cc.lba = lnb[lane]; cc.lbb = lnb[lane + 64];
    cc.gb2 = b2[lane];
    return cc;
}

template<int MODE>
__device__ __forceinline__ void pillar_group(
    int grp, int P, int lane, float* wsw,
    const float* __restrict__ pillars, const int* __restrict__ coors,
    const int* __restrict__ npp, const float* __restrict__ image,
    const float* __restrict__ calibs, const ChanConst& cc,
    const float4* w1rA, const float4* w1rB, const float4* w2r,
    float* __restrict__ feat, int* __restrict__ idxmap, float* __restrict__ out)
{
    const float4* wsf4 = (const float4*)wsw;
    const int pbase = grp * PPG;
    const bool full = (pbase + PPG <= P);

    asm volatile("s_waitcnt lgkmcnt(0)" ::: "memory");
    if (full) {
        const float* src = pillars + (size_t)pbase * (PTS_M * 4);
        gload_lds16(src + lane * 4, wsw);
        gload_lds16(src + 256 + lane * 4, wsw + 256);
    } else {
        #pragma unroll
        for (int h = 0; h < 2; ++h) {
            const int idx = pbase * PTS_M + h * 64 + lane;
            float4 v = make_float4(0.f, 0.f, 0.f, 0.f);
            if (idx < P * PTS_M) v = ((const float4*)pillars)[idx];
            ((float4*)wsw)[h * 64 + lane] = v;
        }
    }

    int bbv[PPG], ixv[PPG], iyv[PPG], nv[PPG];
    #pragma unroll
    for (int pp = 0; pp < PPG; ++pp) {
        const int p = pbase + pp;
        if (p < P) {
            bbv[pp] = coors[p * 3]; ixv[pp] = coors[p * 3 + 1];
            iyv[pp] = coors[p * 3 + 2]; nv[pp] = npp[p];
        } else { bbv[pp] = 0; ixv[pp] = 0; iyv[pp] = 0; nv[pp] = 1; }
    }

    asm volatile("s_waitcnt vmcnt(0) lgkmcnt(0)" ::: "memory");

    const float4 qa = wsf4[lane];
    const float4 qb = wsf4[64 + lane];
    float ax = qa.x, ay = qa.y, az = qa.z;
    float bx = qb.x, by = qb.y, bz = qb.z;
    RED5(ax) RED5(ay) RED5(az)
    RED5(bx) RED5(by) RED5(bz)
    const float axo = __shfl_xor(ax, 32), ayo = __shfl_xor(ay, 32), azo = __shfl_xor(az, 32);
    const float bxo = __shfl_xor(bx, 32), byo = __shfl_xor(by, 32), bzo = __shfl_xor(bz, 32);
    const bool lo = lane < 32;
    float mx[PPG], my[PPG], mz[PPG];
    {
        const float f0 = 1.f / (float)nv[0], f1 = 1.f / (float)nv[1];
        const float f2 = 1.f / (float)nv[2], f3 = 1.f / (float)nv[3];
        mx[0] = (lo ? ax : axo) * f0;  mx[1] = (lo ? axo : ax) * f1;
        my[0] = (lo ? ay : ayo) * f0;  my[1] = (lo ? ayo : ay) * f1;
        mz[0] = (lo ? az : azo) * f0;  mz[1] = (lo ? azo : az) * f1;
        mx[2] = (lo ? bx : bxo) * f2;  mx[3] = (lo ? bxo : bx) * f3;
        my[2] = (lo ? by : byo) * f2;  my[3] = (lo ? byo : by) * f3;
        mz[2] = (lo ? bz : bzo) * f2;  mz[3] = (lo ? bzo : bz) * f3;
    }

    float img[PPG], Es[PPG];
    #pragma unroll
    for (int pp = 0; pp < PPG; ++pp) {
        const float* cb = calibs + bbv[pp] * 12;
        const float pr0 = cb[0]*mx[pp] + cb[1]*my[pp] + cb[2]*mz[pp] + cb[3];
        const float pr1 = cb[4]*mx[pp] + cb[5]*my[pp] + cb[6]*mz[pp] + cb[7];
        const float pr2 = cb[8]*mx[pp] + cb[9]*my[pp] + cb[10]*mz[pp] + cb[11];
        float uf = (pr0 / pr2) * 0.5f;
        float vf = (pr1 / pr2) * 0.5f;
        uf = fminf(fmaxf(uf, 0.f), (float)(WIMG - 1));
        vf = fminf(fmaxf(vf, 0.f), (float)(HIMG - 1));
        const int u = (int)uf, v = (int)vf;
        if (MODE == 2) {
            img[pp] = image[((size_t)bbv[pp] * HW + (size_t)v * WIMG + u) * NCH + lane];
        } else {
            img[pp] = image[(((size_t)(bbv[pp] * NCH + lane)) * HIMG + v) * WIMG + u];
        }
        const float cxp = (float)ixv[pp] * 0.16f + 0.08f;
        const float cyp = (float)iyv[pp] * 0.16f + (-39.6f);
        Es[pp] = cc.tch - (cxp * cc.w07 + cyp * cc.w18 + mx[pp] * cc.w4s + my[pp] * cc.w5s + mz[pp] * cc.w6s);
    }

    float pooled[PPG];
    #pragma unroll
    for (int pp = 0; pp < PPG; ++pp) {
        const int n = nv[pp];
        float p0 = (n < PTS_M) ? cc.tch : -FLT_MAX;
        float p1 = -FLT_MAX, p2 = -FLT_MAX, p3 = -FLT_MAX;
        #pragma unroll
        for (int m = 0; m < PTS_M; m += 4) {
            const float4 q0 = wsf4[pp * 32 + m];
            const float4 q1 = wsf4[pp * 32 + m + 1];
            const float4 q2 = wsf4[pp * 32 + m + 2];
            const float4 q3 = wsf4[pp * 32 + m + 3];
            const float h0 = Es[pp] + q0.x*cc.As + q0.y*cc.Bs + q0.z*cc.Cs + q0.w*cc.Ds;
            const float h1 = Es[pp] + q1.x*cc.As + q1.y*cc.Bs + q1.z*cc.Cs + q1.w*cc.Ds;
            const float h2 = Es[pp] + q2.x*cc.As + q2.y*cc.Bs + q2.z*cc.Cs + q2.w*cc.Ds;
            const float h3 = Es[pp] + q3.x*cc.As + q3.y*cc.Bs + q3.z*cc.Cs + q3.w*cc.Ds;
            p0 = fmaxf(p0, (m     < n) ? h0 : -FLT_MAX);
            p1 = fmaxf(p1, (m + 1 < n) ? h1 : -FLT_MAX);
            p2 = fmaxf(p2, (m + 2 < n) ? h2 : -FLT_MAX);
            p3 = fmaxf(p3, (m + 3 < n) ? h3 : -FLT_MAX);
        }
        pooled[pp] = fmaxf(fmaxf(fmaxf(p0, p1), fmaxf(p2, p3)), 0.f);
    }

    #pragma unroll
    for (int pp = 0; pp < PPG; ++pp) {
        wsw[pp * 128 + lane]      = pooled[pp];
        wsw[pp * 128 + 64 + lane] = img[pp];
    }
    asm volatile("s_waitcnt lgkmcnt(0)" ::: "memory");

    float accA[PPG], accB[PPG];
    #pragma unroll
    for (int pp = 0; pp < PPG; ++pp) { accA[pp] = cc.b1a; accB[pp] = cc.b1b; }
    #pragma unroll 4
    for (int k4 = 0; k4 < 32; ++k4) {
        const float4 wa = w1rA[k4];
        const float4 wb = w1rB[k4];
        #pragma unroll
        for (int pp = 0; pp < PPG; ++pp) {
            const float4 cv = wsf4[pp * 32 + k4];
            accA[pp] += cv.x*wa.x + cv.y*wa.y + cv.z*wa.z + cv.w*wa.w;
            accB[pp] += cv.x*wb.x + cv.y*wb.y + cv.z*wb.z + cv.w*wb.w;
        }
    }

    float sum[PPG], sq[PPG];
    #pragma unroll
    for (int pp = 0; pp < PPG; ++pp) {
        sum[pp] = accA[pp] + accB[pp];
        sq[pp]  = accA[pp]*accA[pp] + accB[pp]*accB[pp];
    }
    #pragma unroll
    for (int d = 32; d; d >>= 1) {
        #pragma unroll
        for (int pp = 0; pp < PPG; ++pp) {
            sum[pp] += __shfl_xor(sum[pp], d);
            sq[pp]  += __shfl_xor(sq[pp], d);
        }
    }
    #pragma unroll
    for (int pp = 0; pp < PPG; ++pp) {
        const float mu  = sum[pp] * (1.f / 128.f);
        const float var = sq[pp] * (1.f / 128.f) - mu * mu;
        const float inv = 1.f / sqrtf(var + 1e-5f);
        const float g0 = (accA[pp] - mu) * inv * cc.lga + cc.lba;
        const float g1 = (accB[pp] - mu) * inv * cc.lgb + cc.lbb;
        wsw[pp * 128 + lane]      = fmaxf(g0, 0.f);
        wsw[pp * 128 + 64 + lane] = fmaxf(g1, 0.f);
    }
    asm volatile("s_waitcnt lgkmcnt(0)" ::: "memory");

    float ac2[PPG];
    #pragma unroll
    for (int pp = 0; pp < PPG; ++pp) ac2[pp] = cc.gb2;
    #pragma unroll 4
    for (int k4 = 0; k4 < 32; ++k4) {
        const float4 w = w2r[k4];
        #pragma unroll
        for (int pp = 0; pp < PPG; ++pp) {
            const float4 gv = wsf4[pp * 32 + k4];
            ac2[pp] += gv.x*w.x + gv.y*w.y + gv.z*w.z + gv.w*w.w;
        }
    }
    #pragma unroll
    for (int pp = 0; pp < PPG; ++pp) {
        const int p = pbase + pp;
        if (p >= P) continue;
        const float gate = 1.f / (1.f + expf(-ac2[pp]));
        const float gf = pooled[pp] * gate + img[pp] * (1.f - gate);
        if (MODE == 0) {
            out[(((bbv[pp] * NCH) + lane) * YL + iyv[pp]) * XL + ixv[pp]] = gf;
        } else {
            feat[(size_t)p * NCH + lane] = gf;
            if (lane == 0)
                idxmap[(bbv[pp] * YL + iyv[pp]) * XL + ixv[pp]] = p + 1;
        }
    }
}

template<int MODE, int REP>
__global__ __launch_bounds__(TPB, 1) void pillar_compute(
    const float* __restrict__ pillars, const int* __restrict__ coors,
    const int* __restrict__ npp, const float* __restrict__ image,
    const float* __restrict__ calibs, const float* __restrict__ conv_w,
    const float* __restrict__ bng, const float* __restrict__ bnb,
    const float* __restrict__ bnm, const float* __restrict__ bnv,
    const float* __restrict__ w1, const float* __restrict__ b1,
    const float* __restrict__ lng, const float* __restrict__ lnb,
    const float* __restrict__ w2, const float* __restrict__ b2,
    float* __restrict__ feat, int* __restrict__ idxmap,
    float* __restrict__ out, int P)
{
    __shared__ float w1p[128 * WPITCH];
    __shared__ float w2p[64 * WPITCH];
    __shared__ float ws[WAVES][512];
    const int tid  = threadIdx.x;
    const int lane = tid & 63;
    const int wv   = tid >> 6;
    for (int i = tid; i < 128 * 32; i += TPB) {
        const int j = i >> 5, k4 = i & 31;
        ((float4*)(w1p + j * WPITCH))[k4] = ((const float4*)w1)[i];
    }
    for (int i = tid; i < 64 * 32; i += TPB) {
        const int j = i >> 5, k4 = i & 31;
        ((float4*)(w2p + j * WPITCH))[k4] = ((const float4*)w2)[i];
    }
    __syncthreads();
    const ChanConst cc = load_chan_consts(lane, conv_w, bng, bnb, bnm, bnv, b1, lng, lnb, b2);
    float* wsw = ws[wv];
    const float4* w1rA = (const float4*)(w1p + lane * WPITCH);
    const float4* w1rB = (const float4*)(w1p + (lane + 64) * WPITCH);
    const float4* w2r  = (const float4*)(w2p + lane * WPITCH);
    const int ntasks = (P + PPG - 1) / PPG;
    for (int rep = 0; rep < REP; ++rep)
        for (int grp = blockIdx.x * WAVES + wv; grp < ntasks; grp += NBLOCKS * WAVES)
            pillar_group<MODE>(grp, P, lane, wsw, pillars, coors, npp, image, calibs,
                               cc, w1rA, w1rB, w2r, feat, idxmap, out);
}

// --------------------------- K2: canvas stream, sparse-row LDS staging
template<int REP>
__global__ __launch_bounds__(256, 4) void canvas_build(
    const float* __restrict__ feat, const int* __restrict__ idxmap,
    float4* __restrict__ out, int NROW)
{
    __shared__ int   idxrow[XL];
    __shared__ int   list_p[128];
    __shared__ int   scnt;
    __shared__ float fr[128][65];            // pitch 65: random-slot reads spread banks
    const int tid  = threadIdx.x;
    const int lane = tid & 63;
    const int wv   = tid >> 6;
    const int NF4  = XL / 4;                 // 108

    for (int rep = 0; rep < REP; ++rep)
    for (int by = blockIdx.x; by < NROW; by += gridDim.x) {
        __syncthreads();                     // prev row's LDS reads done
        if (tid < NF4) ((int4*)idxrow)[tid] = ((const int4*)(idxmap + (size_t)by * XL))[tid];
        __syncthreads();

        if (wv == 0) {                       // wave0: compact scan of nonzeros
            int cnt = 0;
            for (int base = 0; base < XL; base += 64) {
                const int x = base + lane;
                const int pv = (x < XL) ? idxrow[x] : 0;
                const unsigned long long bal = __ballot(pv > 0);
                const int slot = cnt + __popcll(bal & ((1ull << lane) - 1ull));
                if (pv > 0 && slot < 128) {
                    list_p[slot] = pv - 1;
                    idxrow[x] = -(slot + 1);     // remap: staged
                }
                cnt += __popcll(bal);
            }
            if (lane == 0) scnt = cnt;
        }
        __syncthreads();

        const int cnt = min(scnt, 128);      // stage: ~20 pillars x 256B, coalesced
        for (int e = wv; e < cnt; e += 4)
            fr[e][lane] = feat[(size_t)list_p[e] * NCH + lane];
        __syncthreads();

        const int b = by / YL, y = by % YL;
        float4* orow = out + ((size_t)b * NCH * YL + y) * NF4;
        for (int t = tid; t < NCH * NF4; t += 256) {
            const int c = t / NF4, x4 = t - c * NF4;
            const int i0 = idxrow[x4*4+0], i1 = idxrow[x4*4+1];
            const int i2 = idxrow[x4*4+2], i3 = idxrow[x4*4+3];
            float4 o = make_float4(0.f, 0.f, 0.f, 0.f);
            if (i0 < 0) o.x = fr[-i0-1][c];
            if (i1 < 0) o.y = fr[-i1-1][c];
            if (i2 < 0) o.z = fr[-i2-1][c];
            if (i3 < 0) o.w = fr[-i3-1][c];
            if (max(max(i0, i1), max(i2, i3)) > 0) {   // overflow fallback (~never)
                if (i0 > 0) o.x = feat[(size_t)(i0-1) * NCH + c];
                if (i1 > 0) o.y = feat[(size_t)(i1-1) * NCH + c];
                if (i2 > 0) o.z = feat[(size_t)(i2-1) * NCH + c];
                if (i3 > 0) o.w = feat[(size_t)(i3-1) * NCH + c];
            }
            orow[(size_t)c * YL * NF4 + x4] = o;
        }
    }
}

// ---------------------------------------------------------------- host
extern "C" void kernel_launch(void* const* d_in, const int* in_sizes, int n_in,
                              void* d_out, int out_size, void* d_ws, size_t ws_size,
                              hipStream_t stream)
{
    const float* pillars = (const float*)d_in[0];
    const int*   coors   = (const int*)d_in[1];
    const int*   npp     = (const int*)d_in[2];
    const float* image   = (const float*)d_in[3];
    const float* calibs  = (const float*)d_in[4];
    const float* conv_w  = (const float*)d_in[6];
    const float* bng     = (const float*)d_in[7];
    const float* bnb     = (const float*)d_in[8];
    const float* bnm     = (const float*)d_in[9];
    const float* bnv     = (const float*)d_in[10];
    const float* w1      = (const float*)d_in[11];
    const float* b1      = (const float*)d_in[12];
    const float* lng     = (const float*)d_in[13];
    const float* lnb     = (const float*)d_in[14];
    const float* w2      = (const float*)d_in[15];
    const float* b2      = (const float*)d_in[16];
    float* out = (float*)d_out;
    const int P = in_sizes[0] / (PTS_M * 4);
    const int B = in_sizes[3] / (NCH * HW);
    const int NROW = B * YL;

    const size_t featBytes = (size_t)P * NCH * sizeof(float);        // 10.24 MB
    const size_t idxBytes  = (size_t)B * YL * XL * sizeof(int);      //  3.43 MB
    const size_t imgTBytes = (size_t)B * HW * NCH * sizeof(float);   // 125.8 MB

    if (ws_size >= featBytes + idxBytes + imgTBytes) {
        float* feat   = (float*)d_ws;
        int*   idxmap = (int*)((char*)d_ws + featBytes);
        float* imgT   = (float*)((char*)d_ws + featBytes + idxBytes);
        zerofill<<<dim3(880), dim3(256), 0, stream>>>((float4*)idxmap, (int)(idxBytes / 16));
        transpose4<4><<<dim3(B * (HW / 256)), dim3(256), 0, stream>>>(image, imgT, B);
        pillar_compute<2, 4><<<dim3(NBLOCKS), dim3(TPB), 0, stream>>>(
            pillars, coors, npp, imgT, calibs, conv_w, bng, bnb, bnm, bnv,
            w1, b1, lng, lnb, w2, b2, feat, idxmap, nullptr, P);
        canvas_build<6><<<dim3(NROW), dim3(256), 0, stream>>>(feat, idxmap, (float4*)d_out, NROW);
    } else if (ws_size >= featBytes + idxBytes) {
        float* feat   = (float*)d_ws;
        int*   idxmap = (int*)((char*)d_ws + featBytes);
        zerofill<<<dim3(880), dim3(256), 0, stream>>>((float4*)idxmap, (int)(idxBytes / 16));
        pillar_compute<1, 1><<<dim3(NBLOCKS), dim3(TPB), 0, stream>>>(
            pillars, coors, npp, image, calibs, conv_w, bng, bnb, bnm, bnv,
            w1, b1, lng, lnb, w2, b2, feat, idxmap, nullptr, P);
        canvas_build<1><<<dim3(NROW), dim3(256), 0, stream>>>(feat, idxmap, (float4*)d_out, NROW);
    } else {
        zerofill<<<dim3(2048), dim3(256), 0, stream>>>((float4*)d_out, out_size / 4);
        pillar_compute<0, 1><<<dim3(NBLOCKS), dim3(TPB), 0, stream>>>(
            pillars, coors, npp, image, calibs, conv_w, bng, bnb, bnm, bnv,
            w1, b1, lng, lnb, w2, b2, nullptr, nullptr, out, P);
    }
}

// Round 9
// 208.140 us; speedup vs baseline: 3.3921x; 3.3921x over previous
//
#include <hip/hip_runtime.h>
#include <cfloat>
#include <cmath>

// PillarEncoder (MI355X / gfx950): out[b][c][y][x] = (4, 64, 496, 432) fp32
#define XL 432
#define YL 496
#define NCH 64
#define HIMG 192
#define WIMG 640
#define HW (HIMG * WIMG)     // 122880
#define PTS_M 32

#define WAVES 16             // fallback pillar kernel: 1024 thr
#define TPB (WAVES * 64)
#define PPG 4
#define NBLOCKS 256
#define WPITCH 132

typedef const __attribute__((address_space(1))) void* gas_t;
typedef __attribute__((address_space(3))) void* las_t;
typedef short bf16x8 __attribute__((ext_vector_type(8)));
typedef float f32x4  __attribute__((ext_vector_type(4)));

__device__ __forceinline__ void gload_lds16(const float* g, float* l) {
    __builtin_amdgcn_global_load_lds((gas_t)g, (las_t)l, 16, 0, 0);
}

#define RED5(v) { v += __shfl_xor(v, 16); v += __shfl_xor(v, 8); v += __shfl_xor(v, 4); \
                  v += __shfl_xor(v, 2);  v += __shfl_xor(v, 1); }

// ---- split-bf16 helpers: x ~= hi + lo, both bf16; packed u32 = (hi<<16)|lo ----
__device__ __forceinline__ unsigned b16rne(float x) {
    unsigned u = __float_as_uint(x);
    return (u + 0x7FFFu + ((u >> 16) & 1u)) >> 16;
}
__device__ __forceinline__ float b16f(unsigned h) { return __uint_as_float(h << 16); }
__device__ __forceinline__ unsigned pack2(float x) {
    const unsigned hi = b16rne(x);
    const unsigned lo = b16rne(x - b16f(hi));
    return (hi << 16) | lo;
}
__device__ __forceinline__ float unpack2(unsigned p) {
    return b16f(p >> 16) + b16f(p & 0xFFFFu);
}
__device__ __forceinline__ void unpack8(uint4 a, uint4 b, bf16x8& hi, bf16x8& lo) {
    hi = (bf16x8){(short)(a.x>>16),(short)(a.y>>16),(short)(a.z>>16),(short)(a.w>>16),
                  (short)(b.x>>16),(short)(b.y>>16),(short)(b.z>>16),(short)(b.w>>16)};
    lo = (bf16x8){(short)(a.x&0xFFFF),(short)(a.y&0xFFFF),(short)(a.z&0xFFFF),(short)(a.w&0xFFFF),
                  (short)(b.x&0xFFFF),(short)(b.y&0xFFFF),(short)(b.z&0xFFFF),(short)(b.w&0xFFFF)};
}
__device__ __forceinline__ f32x4 shfl4(f32x4 v, int m) {
    f32x4 r;
    r[0] = __shfl_xor(v[0], m); r[1] = __shfl_xor(v[1], m);
    r[2] = __shfl_xor(v[2], m); r[3] = __shfl_xor(v[3], m);
    return r;
}

// ---------------------------------------------------------------- zerofill
__global__ void zerofill(float4* __restrict__ o, int n4) {
    int i = blockIdx.x * blockDim.x + threadIdx.x;
    const int st = gridDim.x * blockDim.x;
    const float4 z = make_float4(0.f, 0.f, 0.f, 0.f);
    for (; i < n4; i += st) o[i] = z;
}

// ---------------------------------- K0: NCHW -> NHWC transpose (validated R8)
__global__ __launch_bounds__(256, 2) void transpose4(
    const float* __restrict__ img, float* __restrict__ imgT, int B)
{
    __shared__ float tt[4][64][65];
    const int tid = threadIdx.x;
    const int NT = HW / 256;
    for (int tile = blockIdx.x; tile < B * NT; tile += gridDim.x) {
        const int b   = tile / NT;
        const int px0 = (tile - b * NT) * 256;
        __syncthreads();
        const float4* base4 = (const float4*)(img + (size_t)b * NCH * HW) + px0 / 4;
        #pragma unroll
        for (int i = tid; i < 64 * 64; i += 256) {
            const int c = i >> 6, f4 = i & 63;
            const float4 v = base4[(size_t)c * (HW / 4) + f4];
            tt[0][c][f4] = v.x; tt[1][c][f4] = v.y;
            tt[2][c][f4] = v.z; tt[3][c][f4] = v.w;
        }
        __syncthreads();
        float4* ob4 = (float4*)(imgT + ((size_t)b * HW + px0) * NCH);
        #pragma unroll
        for (int i = tid; i < 256 * 16; i += 256) {
            const int c4 = i & 15, hw = i >> 4;
            const int j = hw & 3, f4 = hw >> 2;
            float4 o;
            o.x = tt[j][4*c4+0][f4]; o.y = tt[j][4*c4+1][f4];
            o.z = tt[j][4*c4+2][f4]; o.w = tt[j][4*c4+3][f4];
            ob4[(size_t)hw * 16 + c4] = o;
        }
    }
}

// ---------------------------------------------------------------- chan consts
struct ChanConst {
    float As, Bs, Cs, Ds, w07, w18, w4s, w5s, w6s, tch;
    float b1a, b1b, lga, lgb, lba, lbb, gb2;
};
__device__ __forceinline__ ChanConst load_chan_consts(
    int lane, const float* conv_w, const float* bng, const float* bnb,
    const float* bnm, const float* bnv, const float* b1, const float* lng,
    const float* lnb, const float* b2)
{
    ChanConst cc;
    float cw[9];
    #pragma unroll
    for (int i = 0; i < 9; ++i) cw[i] = conv_w[lane * 9 + i];
    const float s = bng[lane] / sqrtf(bnv[lane] + 1e-3f);
    cc.tch = bnb[lane] - bnm[lane] * s;
    cc.As  = (cw[0] + cw[4] + cw[7]) * s;
    cc.Bs  = (cw[1] + cw[5] + cw[8]) * s;
    cc.Cs  = (cw[2] + cw[6]) * s;
    cc.Ds  = cw[3] * s;
    cc.w07 = (cw[0] + cw[7]) * s;
    cc.w18 = (cw[1] + cw[8]) * s;
    cc.w4s = cw[4] * s; cc.w5s = cw[5] * s; cc.w6s = cw[6] * s;
    cc.b1a = b1[lane];  cc.b1b = b1[lane + 64];
    cc.lga = lng[lane]; cc.lgb = lng[lane + 64];
    cc.lba = lnb[lane]; cc.lbb = lnb[lane + 64];
    cc.gb2 = b2[lane];
    return cc;
}

// ================= K1a: encode (means/proj/gather/pooled-max) -> catpack =================
#define EWAVES 4
__global__ __launch_bounds__(EWAVES * 64, 8) void encode_kernel(
    const float* __restrict__ pillars, const int* __restrict__ coors,
    const int* __restrict__ npp, const float* __restrict__ imgT,
    const float* __restrict__ calibs, const float* __restrict__ conv_w,
    const float* __restrict__ bng, const float* __restrict__ bnb,
    const float* __restrict__ bnm, const float* __restrict__ bnv,
    unsigned* __restrict__ catpack, int* __restrict__ idxmap, int P)
{
    __shared__ float ws[EWAVES][512];
    const int tid  = threadIdx.x;
    const int lane = tid & 63;
    const int wv   = tid >> 6;
    float cw9[9];
    #pragma unroll
    for (int i = 0; i < 9; ++i) cw9[i] = conv_w[lane * 9 + i];
    const float s   = bng[lane] / sqrtf(bnv[lane] + 1e-3f);
    const float tch = bnb[lane] - bnm[lane] * s;
    const float As  = (cw9[0] + cw9[4] + cw9[7]) * s;
    const float Bs  = (cw9[1] + cw9[5] + cw9[8]) * s;
    const float Cs  = (cw9[2] + cw9[6]) * s;
    const float Ds  = cw9[3] * s;
    const float w07 = (cw9[0] + cw9[7]) * s;
    const float w18 = (cw9[1] + cw9[8]) * s;
    const float w4s = cw9[4] * s, w5s = cw9[5] * s, w6s = cw9[6] * s;

    float* wsw = ws[wv];
    const float4* wsf4 = (const float4*)wsw;
    const int ntasks = (P + PPG - 1) / PPG;
    const int wstride = gridDim.x * EWAVES;

    for (int grp = blockIdx.x * EWAVES + wv; grp < ntasks; grp += wstride) {
        const int pbase = grp * PPG;
        const bool full = (pbase + PPG <= P);

        asm volatile("s_waitcnt lgkmcnt(0)" ::: "memory");
        if (full) {
            const float* src = pillars + (size_t)pbase * (PTS_M * 4);
            gload_lds16(src + lane * 4, wsw);
            gload_lds16(src + 256 + lane * 4, wsw + 256);
        } else {
            #pragma unroll
            for (int h = 0; h < 2; ++h) {
                const int idx = pbase * PTS_M + h * 64 + lane;
                float4 v = make_float4(0.f, 0.f, 0.f, 0.f);
                if (idx < P * PTS_M) v = ((const float4*)pillars)[idx];
                ((float4*)wsw)[h * 64 + lane] = v;
            }
        }

        int bbv[PPG], ixv[PPG], iyv[PPG], nv[PPG];
        #pragma unroll
        for (int pp = 0; pp < PPG; ++pp) {
            const int p = pbase + pp;
            if (p < P) {
                bbv[pp] = coors[p * 3]; ixv[pp] = coors[p * 3 + 1];
                iyv[pp] = coors[p * 3 + 2]; nv[pp] = npp[p];
            } else { bbv[pp] = 0; ixv[pp] = 0; iyv[pp] = 0; nv[pp] = 1; }
        }

        asm volatile("s_waitcnt vmcnt(0) lgkmcnt(0)" ::: "memory");

        const float4 qa = wsf4[lane];
        const float4 qb = wsf4[64 + lane];
        float ax = qa.x, ay = qa.y, az = qa.z;
        float bx = qb.x, by = qb.y, bz = qb.z;
        RED5(ax) RED5(ay) RED5(az)
        RED5(bx) RED5(by) RED5(bz)
        const float axo = __shfl_xor(ax, 32), ayo = __shfl_xor(ay, 32), azo = __shfl_xor(az, 32);
        const float bxo = __shfl_xor(bx, 32), byo = __shfl_xor(by, 32), bzo = __shfl_xor(bz, 32);
        const bool lo = lane < 32;
        float mx[PPG], my[PPG], mz[PPG];
        {
            const float f0 = 1.f / (float)nv[0], f1 = 1.f / (float)nv[1];
            const float f2 = 1.f / (float)nv[2], f3 = 1.f / (float)nv[3];
            mx[0] = (lo ? ax : axo) * f0;  mx[1] = (lo ? axo : ax) * f1;
            my[0] = (lo ? ay : ayo) * f0;  my[1] = (lo ? ayo : ay) * f1;
            mz[0] = (lo ? az : azo) * f0;  mz[1] = (lo ? azo : az) * f1;
            mx[2] = (lo ? bx : bxo) * f2;  mx[3] = (lo ? bxo : bx) * f3;
            my[2] = (lo ? by : byo) * f2;  my[3] = (lo ? byo : by) * f3;
            mz[2] = (lo ? bz : bzo) * f2;  mz[3] = (lo ? bzo : bz) * f3;
        }

        float img[PPG], Es[PPG];
        #pragma unroll
        for (int pp = 0; pp < PPG; ++pp) {
            const float* cb = calibs + bbv[pp] * 12;
            const float pr0 = cb[0]*mx[pp] + cb[1]*my[pp] + cb[2]*mz[pp] + cb[3];
            const float pr1 = cb[4]*mx[pp] + cb[5]*my[pp] + cb[6]*mz[pp] + cb[7];
            const float pr2 = cb[8]*mx[pp] + cb[9]*my[pp] + cb[10]*mz[pp] + cb[11];
            float uf = (pr0 / pr2) * 0.5f;
            float vf = (pr1 / pr2) * 0.5f;
            uf = fminf(fmaxf(uf, 0.f), (float)(WIMG - 1));
            vf = fminf(fmaxf(vf, 0.f), (float)(HIMG - 1));
            const int u = (int)uf, v = (int)vf;
            img[pp] = imgT[((size_t)bbv[pp] * HW + (size_t)v * WIMG + u) * NCH + lane];
            const float cxp = (float)ixv[pp] * 0.16f + 0.08f;
            const float cyp = (float)iyv[pp] * 0.16f + (-39.6f);
            Es[pp] = tch - (cxp * w07 + cyp * w18 + mx[pp] * w4s + my[pp] * w5s + mz[pp] * w6s);
        }

        #pragma unroll
        for (int pp = 0; pp < PPG; ++pp) {
            const int n = nv[pp];
            float p0 = (n < PTS_M) ? tch : -FLT_MAX;
            float p1 = -FLT_MAX, p2 = -FLT_MAX, p3 = -FLT_MAX;
            #pragma unroll
            for (int m = 0; m < PTS_M; m += 4) {
                const float4 q0 = wsf4[pp * 32 + m];
                const float4 q1 = wsf4[pp * 32 + m + 1];
                const float4 q2 = wsf4[pp * 32 + m + 2];
                const float4 q3 = wsf4[pp * 32 + m + 3];
                const float h0 = Es[pp] + q0.x*As + q0.y*Bs + q0.z*Cs + q0.w*Ds;
                const float h1 = Es[pp] + q1.x*As + q1.y*Bs + q1.z*Cs + q1.w*Ds;
                const float h2 = Es[pp] + q2.x*As + q2.y*Bs + q2.z*Cs + q2.w*Ds;
                const float h3 = Es[pp] + q3.x*As + q3.y*Bs + q3.z*Cs + q3.w*Ds;
                p0 = fmaxf(p0, (m     < n) ? h0 : -FLT_MAX);
                p1 = fmaxf(p1, (m + 1 < n) ? h1 : -FLT_MAX);
                p2 = fmaxf(p2, (m + 2 < n) ? h2 : -FLT_MAX);
                p3 = fmaxf(p3, (m + 3 < n) ? h3 : -FLT_MAX);
            }
            const float pooled = fmaxf(fmaxf(fmaxf(p0, p1), fmaxf(p2, p3)), 0.f);
            const int p = pbase + pp;
            if (p < P) {
                catpack[(size_t)p * 128 + lane]      = pack2(pooled);
                catpack[(size_t)p * 128 + 64 + lane] = pack2(img[pp]);
                if (lane == 0)
                    idxmap[(bbv[pp] * YL + iyv[pp]) * XL + ixv[pp]] = p + 1;
            }
        }
    }
}

// ================= K1b: MFMA MLP (GEMM1 + LN + GEMM2 + gate) =================
// mfma_f32_16x16x32_bf16 layouts: A: row=l&15, k=(l>>4)*8+j. B: col=l&15, same k.
// C/D: col=lane&15, row=(lane>>4)*4+reg  [learn_hip m89].
#define GPITCH 132
__global__ __launch_bounds__(256, 1) void mlp_kernel(
    const unsigned* __restrict__ catpack,
    const float* __restrict__ w1, const float* __restrict__ b1,
    const float* __restrict__ lng, const float* __restrict__ lnb,
    const float* __restrict__ w2, const float* __restrict__ b2,
    float* __restrict__ feat, int P)
{
    __shared__ short w1h[2048 * 8], w1l[2048 * 8];   // 32 KB + 32 KB, frag-linear
    __shared__ short w2h[1024 * 8], w2l[1024 * 8];   // 16 KB + 16 KB
    __shared__ unsigned gpk[64 * GPITCH];            // 33.8 KB (packed g)

    const int tid  = threadIdx.x;
    const int lane = tid & 63;
    const int mt   = tid >> 6;          // wave id = M-tile (16 pillars)
    const int cl   = lane & 15;         // frag col / A row
    const int kg   = lane >> 4;         // k-subgroup (0..3)

    // ---- stage weights as split-bf16 fragment-linear tiles ----
    for (int f = tid; f < 2048; f += 256) {          // w1: kt(4) x nt(8) x lane(64)
        const int l = f & 63, nt = (f >> 6) & 7, kt = f >> 9;
        const int jcol = nt * 16 + (l & 15);
        const int k0 = kt * 32 + (l >> 4) * 8;
        const float4 a = *(const float4*)(w1 + (size_t)jcol * 128 + k0);
        const float4 b = *(const float4*)(w1 + (size_t)jcol * 128 + k0 + 4);
        float v[8] = {a.x, a.y, a.z, a.w, b.x, b.y, b.z, b.w};
        short hi[8], lo[8];
        #pragma unroll
        for (int j = 0; j < 8; ++j) {
            const unsigned h = b16rne(v[j]);
            hi[j] = (short)h;
            lo[j] = (short)b16rne(v[j] - b16f(h));
        }
        #pragma unroll
        for (int j = 0; j < 8; ++j) { w1h[f * 8 + j] = hi[j]; w1l[f * 8 + j] = lo[j]; }
    }
    for (int f = tid; f < 1024; f += 256) {          // w2: kt(4) x nt(4) x lane(64)
        const int l = f & 63, nt = (f >> 6) & 3, kt = f >> 8;
        const int jcol = nt * 16 + (l & 15);
        const int k0 = kt * 32 + (l >> 4) * 8;
        const float4 a = *(const float4*)(w2 + (size_t)jcol * 128 + k0);
        const float4 b = *(const float4*)(w2 + (size_t)jcol * 128 + k0 + 4);
        float v[8] = {a.x, a.y, a.z, a.w, b.x, b.y, b.z, b.w};
        #pragma unroll
        for (int j = 0; j < 8; ++j) {
            const unsigned h = b16rne(v[j]);
            w2h[f * 8 + j] = (short)h;
            w2l[f * 8 + j] = (short)b16rne(v[j] - b16f(h));
        }
    }
    __syncthreads();

    // per-lane bias/LN constants (col-dependent)
    float b1v[8], lgv[8], lbv[8], b2v[4];
    #pragma unroll
    for (int nt = 0; nt < 8; ++nt) {
        b1v[nt] = b1[cl + nt * 16];
        lgv[nt] = lng[cl + nt * 16];
        lbv[nt] = lnb[cl + nt * 16];
    }
    #pragma unroll
    for (int nt = 0; nt < 4; ++nt) b2v[nt] = b2[cl + nt * 16];

    const int ntiles = (P + 63) / 64;
    for (int t = blockIdx.x; t < ntiles; t += gridDim.x) {
        const int pb = t * 64;
        const int row = pb + mt * 16 + cl;           // this lane's A row (pillar)

        // ---- A frags for all 4 K-tiles (global, L2/L3-resident) ----
        bf16x8 ahi[4], alo[4];
        #pragma unroll
        for (int kt = 0; kt < 4; ++kt) {
            const unsigned* src = catpack + (size_t)row * 128 + kt * 32 + kg * 8;
            const uint4 a = *(const uint4*)src;
            const uint4 b = *(const uint4*)(src + 4);
            unpack8(a, b, ahi[kt], alo[kt]);
        }

        // ---- GEMM1: 8 N-tiles, split-bf16 3-pass ----
        f32x4 acc[8];
        #pragma unroll
        for (int nt = 0; nt < 8; ++nt) acc[nt] = (f32x4){b1v[nt], b1v[nt], b1v[nt], b1v[nt]};
        #pragma unroll
        for (int kt = 0; kt < 4; ++kt) {
            #pragma unroll
            for (int nt = 0; nt < 8; ++nt) {
                const bf16x8 bh = *(const bf16x8*)(w1h + ((size_t)((kt * 8 + nt) * 64 + lane)) * 8);
                const bf16x8 bl = *(const bf16x8*)(w1l + ((size_t)((kt * 8 + nt) * 64 + lane)) * 8);
                acc[nt] = __builtin_amdgcn_mfma_f32_16x16x32_bf16(ahi[kt], bh, acc[nt], 0, 0, 0);
                acc[nt] = __builtin_amdgcn_mfma_f32_16x16x32_bf16(ahi[kt], bl, acc[nt], 0, 0, 0);
                acc[nt] = __builtin_amdgcn_mfma_f32_16x16x32_bf16(alo[kt], bh, acc[nt], 0, 0, 0);
            }
        }

        // ---- LayerNorm(128) + relu -> gpk (wave-local rows) ----
        f32x4 sum = acc[0], sq = acc[0] * acc[0];
        #pragma unroll
        for (int nt = 1; nt < 8; ++nt) { sum += acc[nt]; sq += acc[nt] * acc[nt]; }
        #pragma unroll
        for (int m = 8; m; m >>= 1) { sum += shfl4(sum, m); sq += shfl4(sq, m); }
        f32x4 mu = sum * (1.f / 128.f);
        f32x4 inv;
        #pragma unroll
        for (int r = 0; r < 4; ++r) {
            const float var = sq[r] * (1.f / 128.f) - mu[r] * mu[r];
            inv[r] = 1.f / sqrtf(var + 1e-5f);
        }
        #pragma unroll
        for (int nt = 0; nt < 8; ++nt) {
            #pragma unroll
            for (int r = 0; r < 4; ++r) {
                const float g = fmaxf((acc[nt][r] - mu[r]) * inv[r] * lgv[nt] + lbv[nt], 0.f);
                gpk[(mt * 16 + kg * 4 + r) * GPITCH + cl + nt * 16] = pack2(g);
            }
        }
        asm volatile("s_waitcnt lgkmcnt(0)" ::: "memory");   // wave-local LDS handoff

        // ---- GEMM2 ----
        f32x4 ac2[4];
        #pragma unroll
        for (int nt = 0; nt < 4; ++nt) ac2[nt] = (f32x4){b2v[nt], b2v[nt], b2v[nt], b2v[nt]};
        #pragma unroll
        for (int kt = 0; kt < 4; ++kt) {
            const unsigned* gsrc = gpk + (size_t)(mt * 16 + cl) * GPITCH + kt * 32 + kg * 8;
            const uint4 ga = *(const uint4*)gsrc;
            const uint4 gb = *(const uint4*)(gsrc + 4);
            bf16x8 ghi, glo;
            unpack8(ga, gb, ghi, glo);
            #pragma unroll
            for (int nt = 0; nt < 4; ++nt) {
                const bf16x8 bh = *(const bf16x8*)(w2h + ((size_t)((kt * 4 + nt) * 64 + lane)) * 8);
                const bf16x8 bl = *(const bf16x8*)(w2l + ((size_t)((kt * 4 + nt) * 64 + lane)) * 8);
                ac2[nt] = __builtin_amdgcn_mfma_f32_16x16x32_bf16(ghi, bh, ac2[nt], 0, 0, 0);
                ac2[nt] = __builtin_amdgcn_mfma_f32_16x16x32_bf16(ghi, bl, ac2[nt], 0, 0, 0);
                ac2[nt] = __builtin_amdgcn_mfma_f32_16x16x32_bf16(glo, bh, ac2[nt], 0, 0, 0);
            }
        }

        // ---- sigmoid gate + blend + feat store ----
        #pragma unroll
        for (int nt = 0; nt < 4; ++nt) {
            const int col2 = cl + nt * 16;
            #pragma unroll
            for (int r = 0; r < 4; ++r) {
                const int prow = pb + mt * 16 + kg * 4 + r;
                if (prow >= P) continue;
                const unsigned cp = catpack[(size_t)prow * 128 + col2];
                const unsigned ci = catpack[(size_t)prow * 128 + 64 + col2];
                const float pooled = unpack2(cp);
                const float imgv   = unpack2(ci);
                const float gate = 1.f / (1.f + expf(-ac2[nt][r]));
                feat[(size_t)prow * 64 + col2] = pooled * gate + imgv * (1.f - gate);
            }
        }
        __syncthreads();   // gpk reused next tile (cheap: 2.4 tiles/block)
    }
}

// --------------------------- K2: canvas stream (validated R8 sparse staging)
__global__ __launch_bounds__(256, 4) void canvas_build(
    const float* __restrict__ feat, const int* __restrict__ idxmap,
    float4* __restrict__ out, int NROW)
{
    __shared__ int   idxrow[XL];
    __shared__ int   list_p[128];
    __shared__ int   scnt;
    __shared__ float fr[128][65];
    const int tid  = threadIdx.x;
    const int lane = tid & 63;
    const int wv   = tid >> 6;
    const int NF4  = XL / 4;

    for (int by = blockIdx.x; by < NROW; by += gridDim.x) {
        __syncthreads();
        if (tid < NF4) ((int4*)idxrow)[tid] = ((const int4*)(idxmap + (size_t)by * XL))[tid];
        __syncthreads();

        if (wv == 0) {
            int cnt = 0;
            for (int base = 0; base < XL; base += 64) {
                const int x = base + lane;
                const int pv = (x < XL) ? idxrow[x] : 0;
                const unsigned long long bal = __ballot(pv > 0);
                const int slot = cnt + __popcll(bal & ((1ull << lane) - 1ull));
                if (pv > 0 && slot < 128) {
                    list_p[slot] = pv - 1;
                    idxrow[x] = -(slot + 1);
                }
                cnt += __popcll(bal);
            }
            if (lane == 0) scnt = cnt;
        }
        __syncthreads();

        const int cnt = min(scnt, 128);
        for (int e = wv; e < cnt; e += 4)
            fr[e][lane] = feat[(size_t)list_p[e] * NCH + lane];
        __syncthreads();

        const int b = by / YL, y = by % YL;
        float4* orow = out + ((size_t)b * NCH * YL + y) * NF4;
        for (int t = tid; t < NCH * NF4; t += 256) {
            const int c = t / NF4, x4 = t - c * NF4;
            const int i0 = idxrow[x4*4+0], i1 = idxrow[x4*4+1];
            const int i2 = idxrow[x4*4+2], i3 = idxrow[x4*4+3];
            float4 o = make_float4(0.f, 0.f, 0.f, 0.f);
            if (i0 < 0) o.x = fr[-i0-1][c];
            if (i1 < 0) o.y = fr[-i1-1][c];
            if (i2 < 0) o.z = fr[-i2-1][c];
            if (i3 < 0) o.w = fr[-i3-1][c];
            if (max(max(i0, i1), max(i2, i3)) > 0) {
                if (i0 > 0) o.x = feat[(size_t)(i0-1) * NCH + c];
                if (i1 > 0) o.y = feat[(size_t)(i1-1) * NCH + c];
                if (i2 > 0) o.z = feat[(size_t)(i2-1) * NCH + c];
                if (i3 > 0) o.w = feat[(size_t)(i3-1) * NCH + c];
            }
            orow[(size_t)c * YL * NF4 + x4] = o;
        }
    }
}

// =================== fallback: validated R6/R8 fused pillar kernel ===================
template<int MODE>
__device__ __forceinline__ void pillar_group(
    int grp, int P, int lane, float* wsw,
    const float* __restrict__ pillars, const int* __restrict__ coors,
    const int* __restrict__ npp, const float* __restrict__ image,
    const float* __restrict__ calibs, const ChanConst& cc,
    const float4* w1rA, const float4* w1rB, const float4* w2r,
    float* __restrict__ feat, int* __restrict__ idxmap, float* __restrict__ out)
{
    const float4* wsf4 = (const float4*)wsw;
    const int pbase = grp * PPG;
    const bool full = (pbase + PPG <= P);
    asm volatile("s_waitcnt lgkmcnt(0)" ::: "memory");
    if (full) {
        const float* src = pillars + (size_t)pbase * (PTS_M * 4);
        gload_lds16(src + lane * 4, wsw);
        gload_lds16(src + 256 + lane * 4, wsw + 256);
    } else {
        #pragma unroll
        for (int h = 0; h < 2; ++h) {
            const int idx = pbase * PTS_M + h * 64 + lane;
            float4 v = make_float4(0.f, 0.f, 0.f, 0.f);
            if (idx < P * PTS_M) v = ((const float4*)pillars)[idx];
            ((float4*)wsw)[h * 64 + lane] = v;
        }
    }
    int bbv[PPG], ixv[PPG], iyv[PPG], nv[PPG];
    #pragma unroll
    for (int pp = 0; pp < PPG; ++pp) {
        const int p = pbase + pp;
        if (p < P) {
            bbv[pp] = coors[p * 3]; ixv[pp] = coors[p * 3 + 1];
            iyv[pp] = coors[p * 3 + 2]; nv[pp] = npp[p];
        } else { bbv[pp] = 0; ixv[pp] = 0; iyv[pp] = 0; nv[pp] = 1; }
    }
    asm volatile("s_waitcnt vmcnt(0) lgkmcnt(0)" ::: "memory");
    const float4 qa = wsf4[lane];
    const float4 qb = wsf4[64 + lane];
    float ax = qa.x, ay = qa.y, az = qa.z;
    float bx = qb.x, by = qb.y, bz = qb.z;
    RED5(ax) RED5(ay) RED5(az)
    RED5(bx) RED5(by) RED5(bz)
    const float axo = __shfl_xor(ax, 32), ayo = __shfl_xor(ay, 32), azo = __shfl_xor(az, 32);
    const float bxo = __shfl_xor(bx, 32), byo = __shfl_xor(by, 32), bzo = __shfl_xor(bz, 32);
    const bool lo = lane < 32;
    float mx[PPG], my[PPG], mz[PPG];
    {
        const float f0 = 1.f / (float)nv[0], f1 = 1.f / (float)nv[1];
        const float f2 = 1.f / (float)nv[2], f3 = 1.f / (float)nv[3];
        mx[0] = (lo ? ax : axo) * f0;  mx[1] = (lo ? axo : ax) * f1;
        my[0] = (lo ? ay : ayo) * f0;  my[1] = (lo ? ayo : ay) * f1;
        mz[0] = (lo ? az : azo) * f0;  mz[1] = (lo ? azo : az) * f1;
        mx[2] = (lo ? bx : bxo) * f2;  mx[3] = (lo ? bxo : bx) * f3;
        my[2] = (lo ? by : byo) * f2;  my[3] = (lo ? byo : by) * f3;
        mz[2] = (lo ? bz : bzo) * f2;  mz[3] = (lo ? bzo : bz) * f3;
    }
    float img[PPG], Es[PPG];
    #pragma unroll
    for (int pp = 0; pp < PPG; ++pp) {
        const float* cb = calibs + bbv[pp] * 12;
        const float pr0 = cb[0]*mx[pp] + cb[1]*my[pp] + cb[2]*mz[pp] + cb[3];
        const float pr1 = cb[4]*mx[pp] + cb[5]*my[pp] + cb[6]*mz[pp] + cb[7];
        const float pr2 = cb[8]*mx[pp] + cb[9]*my[pp] + cb[10]*mz[pp] + cb[11];
        float uf = (pr0 / pr2) * 0.5f;
        float vf = (pr1 / pr2) * 0.5f;
        uf = fminf(fmaxf(uf, 0.f), (float)(WIMG - 1));
        vf = fminf(fmaxf(vf, 0.f), (float)(HIMG - 1));
        const int u = (int)uf, v = (int)vf;
        if (MODE == 2) {
            img[pp] = image[((size_t)bbv[pp] * HW + (size_t)v * WIMG + u) * NCH + lane];
        } else {
            img[pp] = image[(((size_t)(bbv[pp] * NCH + lane)) * HIMG + v) * WIMG + u];
        }
        const float cxp = (float)ixv[pp] * 0.16f + 0.08f;
        const float cyp = (float)iyv[pp] * 0.16f + (-39.6f);
        Es[pp] = cc.tch - (cxp * cc.w07 + cyp * cc.w18 + mx[pp] * cc.w4s + my[pp] * cc.w5s + mz[pp] * cc.w6s);
    }
    float pooled[PPG];
    #pragma unroll
    for (int pp = 0; pp < PPG; ++pp) {
        const int n = nv[pp];
        float p0 = (n < PTS_M) ? cc.tch : -FLT_MAX;
        float p1 = -FLT_MAX, p2 = -FLT_MAX, p3 = -FLT_MAX;
        #pragma unroll
        for (int m = 0; m < PTS_M; m += 4) {
            const float4 q0 = wsf4[pp * 32 + m];
            const float4 q1 = wsf4[pp * 32 + m + 1];
            const float4 q2 = wsf4[pp * 32 + m + 2];
            const float4 q3 = wsf4[pp * 32 + m + 3];
            const float h0 = Es[pp] + q0.x*cc.As + q0.y*cc.Bs + q0.z*cc.Cs + q0.w*cc.Ds;
            const float h1 = Es[pp] + q1.x*cc.As + q1.y*cc.Bs + q1.z*cc.Cs + q1.w*cc.Ds;
            const float h2 = Es[pp] + q2.x*cc.As + q2.y*cc.Bs + q2.z*cc.Cs + q2.w*cc.Ds;
            const float h3 = Es[pp] + q3.x*cc.As + q3.y*cc.Bs + q3.z*cc.Cs + q3.w*cc.Ds;
            p0 = fmaxf(p0, (m     < n) ? h0 : -FLT_MAX);
            p1 = fmaxf(p1, (m + 1 < n) ? h1 : -FLT_MAX);
            p2 = fmaxf(p2, (m + 2 < n) ? h2 : -FLT_MAX);
            p3 = fmaxf(p3, (m + 3 < n) ? h3 : -FLT_MAX);
        }
        pooled[pp] = fmaxf(fmaxf(fmaxf(p0, p1), fmaxf(p2, p3)), 0.f);
    }
    #pragma unroll
    for (int pp = 0; pp < PPG; ++pp) {
        wsw[pp * 128 + lane]      = pooled[pp];
        wsw[pp * 128 + 64 + lane] = img[pp];
    }
    asm volatile("s_waitcnt lgkmcnt(0)" ::: "memory");
    float accA[PPG], accB[PPG];
    #pragma unroll
    for (int pp = 0; pp < PPG; ++pp) { accA[pp] = cc.b1a; accB[pp] = cc.b1b; }
    #pragma unroll 4
    for (int k4 = 0; k4 < 32; ++k4) {
        const float4 wa = w1rA[k4];
        const float4 wb = w1rB[k4];
        #pragma unroll
        for (int pp = 0; pp < PPG; ++pp) {
            const float4 cv = wsf4[pp * 32 + k4];
            accA[pp] += cv.x*wa.x + cv.y*wa.y + cv.z*wa.z + cv.w*wa.w;
            accB[pp] += cv.x*wb.x + cv.y*wb.y + cv.z*wb.z + cv.w*wb.w;
        }
    }
    float sum[PPG], sq[PPG];
    #pragma unroll
    for (int pp = 0; pp < PPG; ++pp) {
        sum[pp] = accA[pp] + accB[pp];
        sq[pp]  = accA[pp]*accA[pp] + accB[pp]*accB[pp];
    }
    #pragma unroll
    for (int d = 32; d; d >>= 1) {
        #pragma unroll
        for (int pp = 0; pp < PPG; ++pp) {
            sum[pp] += __shfl_xor(sum[pp], d);
            sq[pp]  += __shfl_xor(sq[pp], d);
        }
    }
    #pragma unroll
    for (int pp = 0; pp < PPG; ++pp) {
        const float mu  = sum[pp] * (1.f / 128.f);
        const float var = sq[pp] * (1.f / 128.f) - mu * mu;
        const float inv = 1.f / sqrtf(var + 1e-5f);
        const float g0 = (accA[pp] - mu) * inv * cc.lga + cc.lba;
        const float g1 = (accB[pp] - mu) * inv * cc.lgb + cc.lbb;
        wsw[pp * 128 + lane]      = fmaxf(g0, 0.f);
        wsw[pp * 128 + 64 + lane] = fmaxf(g1, 0.f);
    }
    asm volatile("s_waitcnt lgkmcnt(0)" ::: "memory");
    float ac2[PPG];
    #pragma unroll
    for (int pp = 0; pp < PPG; ++pp) ac2[pp] = cc.gb2;
    #pragma unroll 4
    for (int k4 = 0; k4 < 32; ++k4) {
        const float4 w = w2r[k4];
        #pragma unroll
        for (int pp = 0; pp < PPG; ++pp) {
            const float4 gv = wsf4[pp * 32 + k4];
            ac2[pp] += gv.x*w.x + gv.y*w.y + gv.z*w.z + gv.w*w.w;
        }
    }
    #pragma unroll
    for (int pp = 0; pp < PPG; ++pp) {
        const int p = pbase + pp;
        if (p >= P) continue;
        const float gate = 1.f / (1.f + expf(-ac2[pp]));
        const float gf = pooled[pp] * gate + img[pp] * (1.f - gate);
        if (MODE == 0) {
            out[(((bbv[pp] * NCH) + lane) * YL + iyv[pp]) * XL + ixv[pp]] = gf;
        } else {
            feat[(size_t)p * NCH + lane] = gf;
            if (lane == 0)
                idxmap[(bbv[pp] * YL + iyv[pp]) * XL + ixv[pp]] = p + 1;
        }
    }
}

template<int MODE>
__global__ __launch_bounds__(TPB, 1) void pillar_compute(
    const float* __restrict__ pillars, const int* __restrict__ coors,
    const int* __restrict__ npp, const float* __restrict__ image,
    const float* __restrict__ calibs, const float* __restrict__ conv_w,
    const float* __restrict__ bng, const float* __restrict__ bnb,
    const float* __restrict__ bnm, const float* __restrict__ bnv,
    const float* __restrict__ w1, const float* __restrict__ b1,
    const float* __restrict__ lng, const float* __restrict__ lnb,
    const float* __restrict__ w2, const float* __restrict__ b2,
    float* __restrict__ feat, int* __restrict__ idxmap,
    float* __restrict__ out, int P)
{
    __shared__ float w1p[128 * WPITCH];
    __shared__ float w2p[64 * WPITCH];
    __shared__ float ws[WAVES][512];
    const int tid  = threadIdx.x;
    const int lane = tid & 63;
    const int wv   = tid >> 6;
    for (int i = tid; i < 128 * 32; i += TPB) {
        const int j = i >> 5, k4 = i & 31;
        ((float4*)(w1p + j * WPITCH))[k4] = ((const float4*)w1)[i];
    }
    for (int i = tid; i < 64 * 32; i += TPB) {
        const int j = i >> 5, k4 = i & 31;
        ((float4*)(w2p + j * WPITCH))[k4] = ((const float4*)w2)[i];
    }
    __syncthreads();
    const ChanConst cc = load_chan_consts(lane, conv_w, bng, bnb, bnm, bnv, b1, lng, lnb, b2);
    float* wsw = ws[wv];
    const float4* w1rA = (const float4*)(w1p + lane * WPITCH);
    const float4* w1rB = (const float4*)(w1p + (lane + 64) * WPITCH);
    const float4* w2r  = (const float4*)(w2p + lane * WPITCH);
    const int ntasks = (P + PPG - 1) / PPG;
    for (int grp = blockIdx.x * WAVES + wv; grp < ntasks; grp += NBLOCKS * WAVES)
        pillar_group<MODE>(grp, P, lane, wsw, pillars, coors, npp, image, calibs,
                           cc, w1rA, w1rB, w2r, feat, idxmap, out);
}

// ---------------------------------------------------------------- host
extern "C" void kernel_launch(void* const* d_in, const int* in_sizes, int n_in,
                              void* d_out, int out_size, void* d_ws, size_t ws_size,
                              hipStream_t stream)
{
    const float* pillars = (const float*)d_in[0];
    const int*   coors   = (const int*)d_in[1];
    const int*   npp     = (const int*)d_in[2];
    const float* image   = (const float*)d_in[3];
    const float* calibs  = (const float*)d_in[4];
    const float* conv_w  = (const float*)d_in[6];
    const float* bng     = (const float*)d_in[7];
    const float* bnb     = (const float*)d_in[8];
    const float* bnm     = (const float*)d_in[9];
    const float* bnv     = (const float*)d_in[10];
    const float* w1      = (const float*)d_in[11];
    const float* b1      = (const float*)d_in[12];
    const float* lng     = (const float*)d_in[13];
    const float* lnb     = (const float*)d_in[14];
    const float* w2      = (const float*)d_in[15];
    const float* b2      = (const float*)d_in[16];
    float* out = (float*)d_out;
    const int P = in_sizes[0] / (PTS_M * 4);
    const int B = in_sizes[3] / (NCH * HW);
    const int NROW = B * YL;

    const size_t featBytes = (size_t)P * NCH * sizeof(float);        // 10.24 MB
    const size_t idxBytes  = (size_t)B * YL * XL * sizeof(int);      //  3.43 MB
    const size_t imgTBytes = (size_t)B * HW * NCH * sizeof(float);   // 125.8 MB
    const size_t catBytes  = (size_t)P * 128 * sizeof(unsigned);     // 20.48 MB

    if (ws_size >= featBytes + idxBytes + imgTBytes + catBytes) {
        float*    feat    = (float*)d_ws;
        int*      idxmap  = (int*)((char*)d_ws + featBytes);
        float*    imgT    = (float*)((char*)d_ws + featBytes + idxBytes);
        unsigned* catpack = (unsigned*)((char*)d_ws + featBytes + idxBytes + imgTBytes);
        zerofill<<<dim3(880), dim3(256), 0, stream>>>((float4*)idxmap, (int)(idxBytes / 16));
        transpose4<<<dim3(B * (HW / 256)), dim3(256), 0, stream>>>(image, imgT, B);
        encode_kernel<<<dim3(1024), dim3(EWAVES * 64), 0, stream>>>(
            pillars, coors, npp, imgT, calibs, conv_w, bng, bnb, bnm, bnv,
            catpack, idxmap, P);
        mlp_kernel<<<dim3(256), dim3(256), 0, stream>>>(
            catpack, w1, b1, lng, lnb, w2, b2, feat, P);
        canvas_build<<<dim3(NROW), dim3(256), 0, stream>>>(feat, idxmap, (float4*)d_out, NROW);
    } else if (ws_size >= featBytes + idxBytes + imgTBytes) {
        float* feat   = (float*)d_ws;
        int*   idxmap = (int*)((char*)d_ws + featBytes);
        float* imgT   = (float*)((char*)d_ws + featBytes + idxBytes);
        zerofill<<<dim3(880), dim3(256), 0, stream>>>((float4*)idxmap, (int)(idxBytes / 16));
        transpose4<<<dim3(B * (HW / 256)), dim3(256), 0, stream>>>(image, imgT, B);
        pillar_compute<2><<<dim3(NBLOCKS), dim3(TPB), 0, stream>>>(
            pillars, coors, npp, imgT, calibs, conv_w, bng, bnb, bnm, bnv,
            w1, b1, lng, lnb, w2, b2, feat, idxmap, nullptr, P);
        canvas_build<<<dim3(NROW), dim3(256), 0, stream>>>(feat, idxmap, (float4*)d_out, NROW);
    } else if (ws_size >= featBytes + idxBytes) {
        float* feat   = (float*)d_ws;
        int*   idxmap = (int*)((char*)d_ws + featBytes);
        zerofill<<<dim3(880), dim3(256), 0, stream>>>((float4*)idxmap, (int)(idxBytes / 16));
        pillar_compute<1><<<dim3(NBLOCKS), dim3(TPB), 0, stream>>>(
            pillars, coors, npp, image, calibs, conv_w, bng, bnb, bnm, bnv,
            w1, b1, lng, lnb, w2, b2, feat, idxmap, nullptr, P);
        canvas_build<<<dim3(NROW), dim3(256), 0, stream>>>(feat, idxmap, (float4*)d_out, NROW);
    } else {
        zerofill<<<dim3(2048), dim3(256), 0, stream>>>((float4*)d_out, out_size / 4);
        pillar_compute<0><<<dim3(NBLOCKS), dim3(TPB), 0, stream>>>(
            pillars, coors, npp, image, calibs, conv_w, bng, bnb, bnm, bnv,
            w1, b1, lng, lnb, w2, b2, nullptr, nullptr, out, P);
    }
}